// Round 18
// baseline (334.540 us; speedup 1.0000x reference)
//
#include <hip/hip_runtime.h>
#include <math.h>

#define BB 128
#define SS 128
#define AE 65
#define VE 65
#define TE 129
#define PFD 128
#define FUSED 545025UL
#define FUSEDI 545025
#define VSTRIDE 136            // padded w-stride (multiple of 8)
#define APLANE 8840            // 65*136
#define FPP 574976UL           // padded per-b f16 k-extent = 512*1123
#define FPPI 574976
#define KSP 512
#define NBLK 1123              // FPPI / KSP

typedef _Float16 half4 __attribute__((ext_vector_type(4)));
typedef _Float16 half8 __attribute__((ext_vector_type(8)));
typedef float f32x16 __attribute__((ext_vector_type(16)));

__device__ __forceinline__ void gll16(const void* g, void* l) {
  __builtin_amdgcn_global_load_lds((const __attribute__((address_space(1))) void*)g,
                                   (__attribute__((address_space(3))) void*)l, 16, 0, 0);
}

// ---------------- init: zero accumulators + zero Fh pad holes (merged) ----------
__global__ __launch_bounds__(256) void k_initf(_Float16* __restrict__ Fh,
                                               float* __restrict__ y1pre,
                                               float* __restrict__ normsq,
                                               float* __restrict__ Flast) {
  const int b = blockIdx.x;
  const int tid = threadIdx.x;
  _Float16* base = Fh + (size_t)b * FPP;
  for (int i = tid; i < 29575; i += 256) {   // 65*65*7 w-pad holes
    const int a = i / 455, r = i - a * 455;
    const int v = r / 7, e = r - v * 7;
    base[a * APLANE + v * VSTRIDE + 129 + e] = (_Float16)0.f;
  }
  for (int i = tid; i < 376; i += 256) base[574600 + i] = (_Float16)0.f;
  if (tid < PFD) y1pre[b * PFD + tid] = 0.f;
  if (tid == 128) normsq[b] = 0.f;
  if (tid == 129) Flast[b] = 0.f;
}

// ---------------- core v3: MFMA, hi/lo-split operands (f32-exact fusion) ----------
__global__ __launch_bounds__(256) void k_core(
    const float* __restrict__ audio, const float* __restrict__ vision,
    const float* __restrict__ text, _Float16* __restrict__ Fh,
    float* __restrict__ normsq)
{
  const int b  = blockIdx.x;
  const int gy = blockIdx.y;          // a = 1+8gy .. 8+8gy
  const int gz = blockIdx.z;          // w = 64gz .. 64gz+63
  const int tid = threadIdx.x;
  const int wv = tid >> 6, ln = tid & 63;
  const int lr = ln & 31, hb = ln >> 5;

  __shared__ float    sVt[64][132];   // [v-1][s]
  __shared__ float    sAc[8][132];    // [j][s]
  __shared__ _Float16 sTh[64][136];   // [w-local][s]
  __shared__ _Float16 sTl[64][136];   // prescaled *2048

  {
    const float* vb = vision + (size_t)b * SS * 64;
#pragma unroll
    for (int r = 0; r < 32; ++r) {
      const int e = tid + 256 * r;
      sVt[e & 63][e >> 6] = vb[e];
    }
    const float* ab = audio + (size_t)b * SS * 64 + 8 * gy;
#pragma unroll
    for (int r = 0; r < 4; ++r) {
      const int e = tid + 256 * r;
      sAc[e & 7][e >> 3] = ab[(e >> 3) * 64 + (e & 7)];
    }
    const int wbase = 64 * gz;
    const float* tb = text + (size_t)b * SS * 128;
#pragma unroll
    for (int r = 0; r < 32; ++r) {
      const int e = tid + 256 * r;
      const int s = e >> 6, wl = e & 63;
      const int w = wbase + wl;
      const float val = (w == 0) ? 1.f : tb[s * 128 + w - 1];
      const _Float16 th = (_Float16)val;
      sTh[wl][s] = th;
      sTl[wl][s] = (_Float16)((val - (float)th) * 2048.f);
    }
  }
  __syncthreads();

  float ss = 0.f;
  for (int i = 0; i < 8; ++i) {
    const int u  = 8 * wv + i;
    const int rt = u >> 1, wt = u & 1;
    const int j  = rt >> 1, vh = rt & 1;
    const int v0m = 32 * vh;
    const int wl0 = 32 * wt;

    f32x16 acc = {}, accl = {};
#pragma unroll
    for (int ks = 0; ks < 8; ++ks) {
      const int s0 = 16 * ks + 8 * hb;
      const float4 x0 = *(const float4*)&sVt[v0m + lr][s0];
      const float4 x1 = *(const float4*)&sVt[v0m + lr][s0 + 4];
      const float4 a0 = *(const float4*)&sAc[j][s0];
      const float4 a1 = *(const float4*)&sAc[j][s0 + 4];
      const float pp[8] = {a0.x * x0.x, a0.y * x0.y, a0.z * x0.z, a0.w * x0.w,
                           a1.x * x1.x, a1.y * x1.y, a1.z * x1.z, a1.w * x1.w};
      half8 afh, afl;
#pragma unroll
      for (int e = 0; e < 8; ++e) {
        const _Float16 h = (_Float16)pp[e];
        afh[e] = h;
        afl[e] = (_Float16)((pp[e] - (float)h) * 2048.f);
      }
      const half8 bqh = *(const half8*)&sTh[wl0 + lr][s0];
      const half8 bql = *(const half8*)&sTl[wl0 + lr][s0];
      acc  = __builtin_amdgcn_mfma_f32_32x32x16_f16(afh, bqh, acc,  0, 0, 0);
      accl = __builtin_amdgcn_mfma_f32_32x32x16_f16(afl, bqh, accl, 0, 0, 0);
      accl = __builtin_amdgcn_mfma_f32_32x32x16_f16(afh, bql, accl, 0, 0, 0);
    }

    const int a = 1 + 8 * gy + j;
    _Float16* Fb = Fh + (size_t)b * FPP + (size_t)a * APLANE;
    const int wg = 64 * gz + wl0 + lr;
#pragma unroll
    for (int reg = 0; reg < 16; ++reg) {
      const int crow = (reg & 3) + 8 * (reg >> 2) + 4 * hb;
      const int v = 1 + 32 * vh + crow;
      const float f = acc[reg] + accl[reg] * (1.f / 2048.f);
      ss += f * f;
      Fb[(size_t)v * VSTRIDE + wg] = (_Float16)f;
    }
  }

#pragma unroll
  for (int off = 32; off > 0; off >>= 1) ss += __shfl_down(ss, off);
  if (ln == 0) atomicAdd(&normsq[b], ss);
}

// ---------------- merged boundary planes: gy=0 a-plane, gy=1 v-plane, gy=2 w=128 ---
__global__ __launch_bounds__(256) void k_planes(
    const float* __restrict__ audio, const float* __restrict__ vision,
    const float* __restrict__ text, _Float16* __restrict__ Fh,
    float* __restrict__ Flast, float* __restrict__ normsq)
{
  const int b = blockIdx.x;
  const int which = blockIdx.y;
  const int tid = threadIdx.x;
  const int tw = tid & 15, tv = tid >> 4;
  __shared__ __align__(16) char smem[28800];

  float ss = 0.f;

  if (which == 0) {
    float (*sv)[80]  = (float(*)[80])smem;
    float (*st)[144] = (float(*)[144])(smem + 10240);
    float acc[5][9];
#pragma unroll
    for (int i = 0; i < 5; ++i)
#pragma unroll
      for (int j = 0; j < 9; ++j) acc[i][j] = 0.f;

    for (int c = 0; c < 4; ++c) {
      const int s0 = 32 * c;
      __syncthreads();
      const float* vbase = &vision[((size_t)(b * SS + s0)) * 64];
#pragma unroll
      for (int r = 0; r < 8; ++r) {
        const int e = tid + 256 * r;
        sv[e >> 6][(e & 63) + 1] = vbase[e];
      }
      const float* tbase = &text[((size_t)(b * SS + s0)) * 128];
#pragma unroll
      for (int r = 0; r < 16; ++r) {
        const int e = tid + 256 * r;
        st[e >> 7][(e & 127) + 1] = tbase[e];
      }
      if (tid < 32) { sv[tid][0] = 1.f; st[tid][0] = 1.f; }
      __syncthreads();
      for (int s = 0; s < 32; ++s) {
        float vr[5], tr[9];
#pragma unroll
        for (int i = 0; i < 5; ++i) {
          const int vx = tv + 16 * i;
          vr[i] = (vx < VE) ? sv[s][vx] : 0.f;
        }
#pragma unroll
        for (int j = 0; j < 9; ++j) {
          const int wx = tw + 16 * j;
          tr[j] = (wx < TE) ? st[s][wx] : 0.f;
        }
#pragma unroll
        for (int i = 0; i < 5; ++i)
#pragma unroll
          for (int j = 0; j < 9; ++j) acc[i][j] += vr[i] * tr[j];
      }
    }
    _Float16* Fb = Fh + (size_t)b * FPP;   // a = 0
#pragma unroll
    for (int i = 0; i < 5; ++i) {
      const int v = tv + 16 * i;
      if (v < VE) {
#pragma unroll
        for (int j = 0; j < 9; ++j) {
          const int w = tw + 16 * j;
          if (w < TE) {
            const float m = acc[i][j];
            Fb[(size_t)v * VSTRIDE + w] = (_Float16)m;
            ss += m * m;
          }
        }
      }
    }
  } else if (which == 1) {
    float (*sa)[64]  = (float(*)[64])smem;
    float (*st)[144] = (float(*)[144])(smem + 10240);
    float acc[4][9];
#pragma unroll
    for (int i = 0; i < 4; ++i)
#pragma unroll
      for (int j = 0; j < 9; ++j) acc[i][j] = 0.f;

    for (int c = 0; c < 4; ++c) {
      const int s0 = 32 * c;
      __syncthreads();
      const float* abase = &audio[((size_t)(b * SS + s0)) * 64];
#pragma unroll
      for (int r = 0; r < 8; ++r) {
        const int e = tid + 256 * r;
        sa[e >> 6][e & 63] = abase[e];
      }
      const float* tbase = &text[((size_t)(b * SS + s0)) * 128];
#pragma unroll
      for (int r = 0; r < 16; ++r) {
        const int e = tid + 256 * r;
        st[e >> 7][(e & 127) + 1] = tbase[e];
      }
      if (tid < 32) st[tid][0] = 1.f;
      __syncthreads();
      for (int s = 0; s < 32; ++s) {
        float ar[4], tr[9];
#pragma unroll
        for (int i = 0; i < 4; ++i) ar[i] = sa[s][tv + 16 * i];
#pragma unroll
        for (int j = 0; j < 9; ++j) {
          const int wx = tw + 16 * j;
          tr[j] = (wx < TE) ? st[s][wx] : 0.f;
        }
#pragma unroll
        for (int i = 0; i < 4; ++i)
#pragma unroll
          for (int j = 0; j < 9; ++j) acc[i][j] += ar[i] * tr[j];
      }
    }
#pragma unroll
    for (int i = 0; i < 4; ++i) {
      const int a = 1 + tv + 16 * i;
      _Float16* Fb = Fh + (size_t)b * FPP + (size_t)a * APLANE;   // v = 0
#pragma unroll
      for (int j = 0; j < 9; ++j) {
        const int w = tw + 16 * j;
        if (w < TE) {
          const float m = acc[i][j];
          Fb[w] = (_Float16)m;
          ss += m * m;
        }
      }
    }
  } else {
    float (*sa)[64] = (float(*)[64])smem;
    float (*sv)[64] = (float(*)[64])(smem + 10240);
    float* swt = (float*)(smem + 10240 + 8192);
    float acc[4][4];
#pragma unroll
    for (int i = 0; i < 4; ++i)
#pragma unroll
      for (int j = 0; j < 4; ++j) acc[i][j] = 0.f;

    for (int c = 0; c < 4; ++c) {
      const int s0 = 32 * c;
      __syncthreads();
      const float* abase = &audio[((size_t)(b * SS + s0)) * 64];
      const float* vbase = &vision[((size_t)(b * SS + s0)) * 64];
#pragma unroll
      for (int r = 0; r < 8; ++r) {
        const int e = tid + 256 * r;
        sa[e >> 6][e & 63] = abase[e];
        sv[e >> 6][e & 63] = vbase[e];
      }
      if (tid < 32) swt[tid] = text[((size_t)(b * SS + s0 + tid)) * 128 + 127];
      __syncthreads();
      for (int s = 0; s < 32; ++s) {
        const float t = swt[s];
        float ar[4], vr[4];
#pragma unroll
        for (int i = 0; i < 4; ++i) ar[i] = sa[s][tv + 16 * i] * t;
#pragma unroll
        for (int j = 0; j < 4; ++j) vr[j] = sv[s][tw + 16 * j];
#pragma unroll
        for (int i = 0; i < 4; ++i)
#pragma unroll
          for (int j = 0; j < 4; ++j) acc[i][j] += ar[i] * vr[j];
      }
    }
#pragma unroll
    for (int i = 0; i < 4; ++i) {
      const int a = 1 + tv + 16 * i;
      _Float16* Fb = Fh + (size_t)b * FPP + (size_t)a * APLANE;
#pragma unroll
      for (int j = 0; j < 4; ++j) {
        const int v = 1 + tw + 16 * j;
        float m = acc[i][j];
        ss += m * m;
        if (a == 64 && v == 64) { Flast[b] = m; m = 0.f; }  // exact fp32 path
        Fb[(size_t)v * VSTRIDE + 128] = (_Float16)m;
      }
    }
  }

#pragma unroll
  for (int off = 32; off > 0; off >>= 1) ss += __shfl_down(ss, off);
  if ((tid & 63) == 0) atomicAdd(&normsq[b], ss);
}

// ---------------- deep-K MFMA GEMM v12: coalesced A + counted vmcnt + 5 blk/CU ----
// grid 1123 (KSP=512 -> 16 steps of 32 k). 4 waves; wave wv owns p-rows [32wv,+32).
// A: instr n reads 4 rows x 128B coalesced (8 lanes/row); cvt f16; per-wave sA
//    transpose (2 KB/wave, slot ^= row&3). B: 3 x 8 KB LDS buffers, staged 2 ahead.
// Step top: s_waitcnt vmcnt(2) retires A(t)+B(t); B(t+1)'s 2 DMAs stay in flight
// across the raw s_barrier. LDS 32 KB total -> ~5 blocks/CU.
__global__ __launch_bounds__(256) void k_gemm(
    const float* __restrict__ W1, const _Float16* __restrict__ Fh,
    float* __restrict__ parts)
{
  __shared__ _Float16 sB3[3][4096];  // 3 x 8 KB
  __shared__ _Float16 sA[4][1024];   // per-wave 32 rows x 32 k f16 (2 KB each)

  const int tid = threadIdx.x;
  const int wv = tid >> 6, ln = tid & 63;
  const int lb = ln & 31, hb = ln >> 5;
  const int kp0 = blockIdx.x * KSP;

  // A-load geometry: instr n covers rows 32wv + 8n + (ln>>3); lane k-off (ln&7)*4
  int wtr, kot;
  {
    const int kpl = kp0 + ((ln & 7) << 2);
    const int a = kpl / APLANE;
    const int rem = kpl - a * APLANE;
    const int v = rem / VSTRIDE;
    wtr = rem - v * VSTRIDE;
    kot = a * 8385 + v * 129 + wtr;
  }
  const float* wbase = W1 + (size_t)((wv << 5) + (ln >> 3)) * FUSED;

  // B staging (r14 lane map): row brow0/brow0+16, pre-swizzled source slot
  const int brow0 = (wv << 5) + (ln >> 2);
  const int slogB = (ln & 3) ^ ((ln >> 2) & 3);
  const _Float16* FhP0 = Fh + (size_t)brow0 * FPP + kp0 + (slogB << 3);
  const _Float16* FhP1 = FhP0 + (size_t)16 * FPP;

  f32x16 acc0 = {}, acc1 = {}, acc2 = {}, acc3 = {};
  float4 xa[4];

  // 4-float chunks never straddle VSTRIDE rows (136 % 4 == 0). Clamp ko<=545021
  // reads valid memory; clamped positions are pad holes/tail where Fh==0.
#define LOADA                                                              \
  {                                                                        \
    const int kc = (kot <= 545021) ? kot : 545021;                         \
    _Pragma("unroll")                                                      \
    for (int n = 0; n < 4; ++n)                                            \
      __builtin_memcpy(&xa[n], wbase + (size_t)(8 * n) * FUSED + kc, 16);  \
    wtr += 32;                                                             \
    if (wtr >= VSTRIDE) { wtr -= VSTRIDE; kot += 25; } else kot += 32;     \
  }

  // cvt + transpose into per-wave sA; row Rl = 8n+(ln>>3); slot ((ln&7)>>1)^(Rl&3)
#define WRITEA                                                             \
  {                                                                        \
    _Pragma("unroll")                                                      \
    for (int n = 0; n < 4; ++n) {                                          \
      const int Rl = 8 * n + (ln >> 3);                                    \
      const int sp = (((ln & 7) >> 1) ^ (Rl & 3));                         \
      half4 h;                                                             \
      h[0] = (_Float16)xa[n].x; h[1] = (_Float16)xa[n].y;                  \
      h[2] = (_Float16)xa[n].z; h[3] = (_Float16)xa[n].w;                  \
      *(half4*)((char*)&sA[wv][0] + (Rl << 6) + (sp << 4) + ((ln & 1) << 3)) = h; \
    }                                                                      \
  }

#define STAGEB(BUF, KOFF)                                                  \
  {                                                                        \
    gll16(FhP0 + (KOFF), (char*)&sB3[BUF][0] + ((wv << 5) << 6));          \
    gll16(FhP1 + (KOFF), (char*)&sB3[BUF][0] + (((wv << 5) + 16) << 6));   \
  }

#define GSTEP(T, WSTR)                                                         \
  {                                                                            \
    asm volatile("s_waitcnt " WSTR ::: "memory");                              \
    __builtin_amdgcn_sched_barrier(0);                                         \
    __builtin_amdgcn_s_barrier();                                              \
    __builtin_amdgcn_sched_barrier(0);                                         \
    WRITEA                                                                     \
    if ((T) + 1 < 16) { LOADA }                                                \
    if ((T) + 2 < 16) { STAGEB(((T) + 2) % 3, ((T) + 2) * 32) }                \
    __builtin_amdgcn_sched_barrier(0);                                         \
    {                                                                          \
      const _Float16* sBb = &sB3[(T) % 3][0];                                  \
      const char* sAw = (const char*)&sA[wv][0] + (lb << 6);                   \
      {                                                                        \
        const int sl = hb;                                                     \
        const half8 af = *(const half8*)(sAw + ((sl ^ (lb & 3)) << 4));        \
        const char* bbase = (const char*)sBb + (lb << 6) + ((sl ^ (lb & 3)) << 4); \
        const half8 b0 = *(const half8*)(bbase);                               \
        const half8 b1 = *(const half8*)(bbase + 2048);                        \
        const half8 b2 = *(const half8*)(bbase + 4096);                        \
        const half8 b3 = *(const half8*)(bbase + 6144);                        \
        acc0 = __builtin_amdgcn_mfma_f32_32x32x16_f16(af, b0, acc0, 0, 0, 0);  \
        acc1 = __builtin_amdgcn_mfma_f32_32x32x16_f16(af, b1, acc1, 0, 0, 0);  \
        acc2 = __builtin_amdgcn_mfma_f32_32x32x16_f16(af, b2, acc2, 0, 0, 0);  \
        acc3 = __builtin_amdgcn_mfma_f32_32x32x16_f16(af, b3, acc3, 0, 0, 0);  \
      }                                                                        \
      {                                                                        \
        const int sl = 2 + hb;                                                 \
        const half8 af = *(const half8*)(sAw + ((sl ^ (lb & 3)) << 4));        \
        const char* bbase = (const char*)sBb + (lb << 6) + ((sl ^ (lb & 3)) << 4); \
        const half8 b0 = *(const half8*)(bbase);                               \
        const half8 b1 = *(const half8*)(bbase + 2048);                        \
        const half8 b2 = *(const half8*)(bbase + 4096);                        \
        const half8 b3 = *(const half8*)(bbase + 6144);                        \
        acc0 = __builtin_amdgcn_mfma_f32_32x32x16_f16(af, b0, acc0, 0, 0, 0);  \
        acc1 = __builtin_amdgcn_mfma_f32_32x32x16_f16(af, b1, acc1, 0, 0, 0);  \
        acc2 = __builtin_amdgcn_mfma_f32_32x32x16_f16(af, b2, acc2, 0, 0, 0);  \
        acc3 = __builtin_amdgcn_mfma_f32_32x32x16_f16(af, b3, acc3, 0, 0, 0);  \
      }                                                                        \
    }                                                                          \
  }

  // prologue: B(0), A(0), B(1) in flight (8 outstanding; oldest = B(0))
  STAGEB(0, 0)
  LOADA
  STAGEB(1, 32)

  GSTEP(0,  "vmcnt(2)")
  GSTEP(1,  "vmcnt(2)")
  GSTEP(2,  "vmcnt(2)")
  GSTEP(3,  "vmcnt(2)")
  GSTEP(4,  "vmcnt(2)")
  GSTEP(5,  "vmcnt(2)")
  GSTEP(6,  "vmcnt(2)")
  GSTEP(7,  "vmcnt(2)")
  GSTEP(8,  "vmcnt(2)")
  GSTEP(9,  "vmcnt(2)")
  GSTEP(10, "vmcnt(2)")
  GSTEP(11, "vmcnt(2)")
  GSTEP(12, "vmcnt(2)")
  GSTEP(13, "vmcnt(2)")
  GSTEP(14, "vmcnt(2)")
  GSTEP(15, "vmcnt(0)")
#undef GSTEP
#undef LOADA
#undef WRITEA
#undef STAGEB

  // coalesced partial store: thread's 64 floats contiguous
  f32x16* o = (f32x16*)(parts + ((size_t)blockIdx.x * 256 + tid) * 64);
  o[0] = acc0; o[1] = acc1; o[2] = acc2; o[3] = acc3;
}

// ---------------- reduce partials -> y1pre[b][p] ----------------
__global__ __launch_bounds__(256) void k_red(const float* __restrict__ parts,
                                             float* __restrict__ y1pre)
{
  const int tid = threadIdx.x;
  const int T = blockIdx.x * 4 + (tid >> 6);
  const int R = tid & 63;
  float s = 0.f;
  for (int sl = blockIdx.y; sl < NBLK; sl += 16)
    s += parts[(size_t)sl * 16384 + T * 64 + R];
  const int wv2 = T >> 6, hb2 = (T >> 5) & 1, lb2 = T & 31;
  const int q = R >> 4, rg = R & 15;
  const int b = q * 32 + lb2;
  const int pp = wv2 * 32 + (rg & 3) + 8 * (rg >> 2) + 4 * hb2;
  atomicAdd(&y1pre[b * PFD + pp], s);
}

// ---------------- finalize: MLP per batch + (block 0) reg_loss ----------------
__global__ __launch_bounds__(128) void k_final(
    const float* __restrict__ y1pre, const float* __restrict__ b1,
    const float* __restrict__ W2, const float* __restrict__ b2,
    const float* __restrict__ W3, const float* __restrict__ b3,
    const float* __restrict__ W1, const float* __restrict__ Flast,
    const float* __restrict__ normsq, float* __restrict__ out)
{
  const int b = blockIdx.x, p = threadIdx.x;
  __shared__ float y1[PFD];
  __shared__ float red[PFD];
  const float extra = W1[(size_t)p * FUSED + (FUSED - 1)] * Flast[b];
  y1[p] = fmaxf(y1pre[(size_t)b * PFD + p] + extra + b1[p], 0.f);
  __syncthreads();
  float s = b2[p];
  for (int k = 0; k < PFD; ++k) s += y1[k] * W2[p * PFD + k];
  const float y2 = fmaxf(s, 0.f);
  red[p] = y2 * W3[p];
  __syncthreads();
  for (int off = 64; off > 0; off >>= 1) {
    if (p < off) red[p] += red[p + off];
    __syncthreads();
  }
  if (p == 0) {
    const float x = red[0] + b3[0];
    out[b] = 6.f / (1.f + expf(-x)) - 3.f;
  }
  if (b == 0) {   // fused k_reg: tmp = sqrt(64*64*128/128) = 64 exactly
    __syncthreads();
    red[p] = sqrtf(normsq[p]);
    __syncthreads();
    for (int off = 64; off > 0; off >>= 1) {
      if (p < off) red[p] += red[p + off];
      __syncthreads();
    }
    if (p == 0) out[BB] = 64.f * red[0] / (float)BB;
  }
}

extern "C" void kernel_launch(void* const* d_in, const int* in_sizes, int n_in,
                              void* d_out, int out_size, void* d_ws, size_t ws_size,
                              hipStream_t stream) {
  const float* audio  = (const float*)d_in[0];
  const float* vision = (const float*)d_in[1];
  const float* text   = (const float*)d_in[2];
  const float* W1     = (const float*)d_in[3];
  const float* b1     = (const float*)d_in[4];
  const float* W2     = (const float*)d_in[5];
  const float* b2     = (const float*)d_in[6];
  const float* W3     = (const float*)d_in[7];
  const float* b3     = (const float*)d_in[8];
  float* out = (float*)d_out;

  // ws layout (proven bound ws >= 279,183,872 B):
  // [y1pre 64KB][normsq][Flast] | Fh @131072 (147,193,856 B) |
  // parts @147,324,928 (1123*64KB = 73,596,928 B) -> total 220,921,856 B
  float* y1pre  = (float*)d_ws;
  float* normsq = y1pre + BB * PFD;
  float* Flast  = normsq + BB;
  _Float16* Fh  = (_Float16*)((char*)d_ws + 131072);
  float* parts  = (float*)((char*)d_ws + 147324928);

  k_initf<<<BB, 256, 0, stream>>>(Fh, y1pre, normsq, Flast);

  k_core<<<dim3(BB, 8, 2), 256, 0, stream>>>(audio, vision, text, Fh, normsq);
  k_planes<<<dim3(BB, 3), 256, 0, stream>>>(audio, vision, text, Fh, Flast, normsq);

  k_gemm<<<NBLK, 256, 0, stream>>>(W1, Fh, parts);
  k_red<<<dim3(64, 16), 256, 0, stream>>>(parts, y1pre);

  k_final<<<BB, PFD, 0, stream>>>(y1pre, b1, W2, b2, W3, b3, W1, Flast, normsq, out);
}

// Round 19
// 313.719 us; speedup vs baseline: 1.0664x; 1.0664x over previous
//
#include <hip/hip_runtime.h>
#include <math.h>

#define BB 128
#define SS 128
#define AE 65
#define VE 65
#define TE 129
#define PFD 128
#define FUSED 545025UL
#define FUSEDI 545025
#define VSTRIDE 136            // padded w-stride (multiple of 8)
#define APLANE 8840            // 65*136
#define FPP 574976UL           // padded per-b f16 k-extent = 512*1123
#define FPPI 574976
#define KSP 512
#define NBLK 1123              // FPPI / KSP
#define NST 8                  // 8 steps x 64 k

typedef _Float16 half4 __attribute__((ext_vector_type(4)));
typedef _Float16 half8 __attribute__((ext_vector_type(8)));
typedef float f32x16 __attribute__((ext_vector_type(16)));

__device__ __forceinline__ void gll16(const void* g, void* l) {
  __builtin_amdgcn_global_load_lds((const __attribute__((address_space(1))) void*)g,
                                   (__attribute__((address_space(3))) void*)l, 16, 0, 0);
}

// ---------------- init: zero accumulators + zero Fh pad holes (merged) ----------
__global__ __launch_bounds__(256) void k_initf(_Float16* __restrict__ Fh,
                                               float* __restrict__ y1pre,
                                               float* __restrict__ normsq,
                                               float* __restrict__ Flast) {
  const int b = blockIdx.x;
  const int tid = threadIdx.x;
  _Float16* base = Fh + (size_t)b * FPP;
  for (int i = tid; i < 29575; i += 256) {   // 65*65*7 w-pad holes
    const int a = i / 455, r = i - a * 455;
    const int v = r / 7, e = r - v * 7;
    base[a * APLANE + v * VSTRIDE + 129 + e] = (_Float16)0.f;
  }
  for (int i = tid; i < 376; i += 256) base[574600 + i] = (_Float16)0.f;
  if (tid < PFD) y1pre[b * PFD + tid] = 0.f;
  if (tid == 128) normsq[b] = 0.f;
  if (tid == 129) Flast[b] = 0.f;
}

// ---------------- core v3: MFMA, hi/lo-split operands (f32-exact fusion) ----------
__global__ __launch_bounds__(256) void k_core(
    const float* __restrict__ audio, const float* __restrict__ vision,
    const float* __restrict__ text, _Float16* __restrict__ Fh,
    float* __restrict__ normsq)
{
  const int b  = blockIdx.x;
  const int gy = blockIdx.y;          // a = 1+8gy .. 8+8gy
  const int gz = blockIdx.z;          // w = 64gz .. 64gz+63
  const int tid = threadIdx.x;
  const int wv = tid >> 6, ln = tid & 63;
  const int lr = ln & 31, hb = ln >> 5;

  __shared__ float    sVt[64][132];   // [v-1][s]
  __shared__ float    sAc[8][132];    // [j][s]
  __shared__ _Float16 sTh[64][136];   // [w-local][s]
  __shared__ _Float16 sTl[64][136];   // prescaled *2048

  {
    const float* vb = vision + (size_t)b * SS * 64;
#pragma unroll
    for (int r = 0; r < 32; ++r) {
      const int e = tid + 256 * r;
      sVt[e & 63][e >> 6] = vb[e];
    }
    const float* ab = audio + (size_t)b * SS * 64 + 8 * gy;
#pragma unroll
    for (int r = 0; r < 4; ++r) {
      const int e = tid + 256 * r;
      sAc[e & 7][e >> 3] = ab[(e >> 3) * 64 + (e & 7)];
    }
    const int wbase = 64 * gz;
    const float* tb = text + (size_t)b * SS * 128;
#pragma unroll
    for (int r = 0; r < 32; ++r) {
      const int e = tid + 256 * r;
      const int s = e >> 6, wl = e & 63;
      const int w = wbase + wl;
      const float val = (w == 0) ? 1.f : tb[s * 128 + w - 1];
      const _Float16 th = (_Float16)val;
      sTh[wl][s] = th;
      sTl[wl][s] = (_Float16)((val - (float)th) * 2048.f);
    }
  }
  __syncthreads();

  float ss = 0.f;
  for (int i = 0; i < 8; ++i) {
    const int u  = 8 * wv + i;
    const int rt = u >> 1, wt = u & 1;
    const int j  = rt >> 1, vh = rt & 1;
    const int v0m = 32 * vh;
    const int wl0 = 32 * wt;

    f32x16 acc = {}, accl = {};
#pragma unroll
    for (int ks = 0; ks < 8; ++ks) {
      const int s0 = 16 * ks + 8 * hb;
      const float4 x0 = *(const float4*)&sVt[v0m + lr][s0];
      const float4 x1 = *(const float4*)&sVt[v0m + lr][s0 + 4];
      const float4 a0 = *(const float4*)&sAc[j][s0];
      const float4 a1 = *(const float4*)&sAc[j][s0 + 4];
      const float pp[8] = {a0.x * x0.x, a0.y * x0.y, a0.z * x0.z, a0.w * x0.w,
                           a1.x * x1.x, a1.y * x1.y, a1.z * x1.z, a1.w * x1.w};
      half8 afh, afl;
#pragma unroll
      for (int e = 0; e < 8; ++e) {
        const _Float16 h = (_Float16)pp[e];
        afh[e] = h;
        afl[e] = (_Float16)((pp[e] - (float)h) * 2048.f);
      }
      const half8 bqh = *(const half8*)&sTh[wl0 + lr][s0];
      const half8 bql = *(const half8*)&sTl[wl0 + lr][s0];
      acc  = __builtin_amdgcn_mfma_f32_32x32x16_f16(afh, bqh, acc,  0, 0, 0);
      accl = __builtin_amdgcn_mfma_f32_32x32x16_f16(afl, bqh, accl, 0, 0, 0);
      accl = __builtin_amdgcn_mfma_f32_32x32x16_f16(afh, bql, accl, 0, 0, 0);
    }

    const int a = 1 + 8 * gy + j;
    _Float16* Fb = Fh + (size_t)b * FPP + (size_t)a * APLANE;
    const int wg = 64 * gz + wl0 + lr;
#pragma unroll
    for (int reg = 0; reg < 16; ++reg) {
      const int crow = (reg & 3) + 8 * (reg >> 2) + 4 * hb;
      const int v = 1 + 32 * vh + crow;
      const float f = acc[reg] + accl[reg] * (1.f / 2048.f);
      ss += f * f;
      Fb[(size_t)v * VSTRIDE + wg] = (_Float16)f;
    }
  }

#pragma unroll
  for (int off = 32; off > 0; off >>= 1) ss += __shfl_down(ss, off);
  if (ln == 0) atomicAdd(&normsq[b], ss);
}

// ---------------- merged boundary planes: gy=0 a-plane, gy=1 v-plane, gy=2 w=128 ---
__global__ __launch_bounds__(256) void k_planes(
    const float* __restrict__ audio, const float* __restrict__ vision,
    const float* __restrict__ text, _Float16* __restrict__ Fh,
    float* __restrict__ Flast, float* __restrict__ normsq)
{
  const int b = blockIdx.x;
  const int which = blockIdx.y;
  const int tid = threadIdx.x;
  const int tw = tid & 15, tv = tid >> 4;
  __shared__ __align__(16) char smem[28800];

  float ss = 0.f;

  if (which == 0) {
    float (*sv)[80]  = (float(*)[80])smem;
    float (*st)[144] = (float(*)[144])(smem + 10240);
    float acc[5][9];
#pragma unroll
    for (int i = 0; i < 5; ++i)
#pragma unroll
      for (int j = 0; j < 9; ++j) acc[i][j] = 0.f;

    for (int c = 0; c < 4; ++c) {
      const int s0 = 32 * c;
      __syncthreads();
      const float* vbase = &vision[((size_t)(b * SS + s0)) * 64];
#pragma unroll
      for (int r = 0; r < 8; ++r) {
        const int e = tid + 256 * r;
        sv[e >> 6][(e & 63) + 1] = vbase[e];
      }
      const float* tbase = &text[((size_t)(b * SS + s0)) * 128];
#pragma unroll
      for (int r = 0; r < 16; ++r) {
        const int e = tid + 256 * r;
        st[e >> 7][(e & 127) + 1] = tbase[e];
      }
      if (tid < 32) { sv[tid][0] = 1.f; st[tid][0] = 1.f; }
      __syncthreads();
      for (int s = 0; s < 32; ++s) {
        float vr[5], tr[9];
#pragma unroll
        for (int i = 0; i < 5; ++i) {
          const int vx = tv + 16 * i;
          vr[i] = (vx < VE) ? sv[s][vx] : 0.f;
        }
#pragma unroll
        for (int j = 0; j < 9; ++j) {
          const int wx = tw + 16 * j;
          tr[j] = (wx < TE) ? st[s][wx] : 0.f;
        }
#pragma unroll
        for (int i = 0; i < 5; ++i)
#pragma unroll
          for (int j = 0; j < 9; ++j) acc[i][j] += vr[i] * tr[j];
      }
    }
    _Float16* Fb = Fh + (size_t)b * FPP;   // a = 0
#pragma unroll
    for (int i = 0; i < 5; ++i) {
      const int v = tv + 16 * i;
      if (v < VE) {
#pragma unroll
        for (int j = 0; j < 9; ++j) {
          const int w = tw + 16 * j;
          if (w < TE) {
            const float m = acc[i][j];
            Fb[(size_t)v * VSTRIDE + w] = (_Float16)m;
            ss += m * m;
          }
        }
      }
    }
  } else if (which == 1) {
    float (*sa)[64]  = (float(*)[64])smem;
    float (*st)[144] = (float(*)[144])(smem + 10240);
    float acc[4][9];
#pragma unroll
    for (int i = 0; i < 4; ++i)
#pragma unroll
      for (int j = 0; j < 9; ++j) acc[i][j] = 0.f;

    for (int c = 0; c < 4; ++c) {
      const int s0 = 32 * c;
      __syncthreads();
      const float* abase = &audio[((size_t)(b * SS + s0)) * 64];
#pragma unroll
      for (int r = 0; r < 8; ++r) {
        const int e = tid + 256 * r;
        sa[e >> 6][e & 63] = abase[e];
      }
      const float* tbase = &text[((size_t)(b * SS + s0)) * 128];
#pragma unroll
      for (int r = 0; r < 16; ++r) {
        const int e = tid + 256 * r;
        st[e >> 7][(e & 127) + 1] = tbase[e];
      }
      if (tid < 32) st[tid][0] = 1.f;
      __syncthreads();
      for (int s = 0; s < 32; ++s) {
        float ar[4], tr[9];
#pragma unroll
        for (int i = 0; i < 4; ++i) ar[i] = sa[s][tv + 16 * i];
#pragma unroll
        for (int j = 0; j < 9; ++j) {
          const int wx = tw + 16 * j;
          tr[j] = (wx < TE) ? st[s][wx] : 0.f;
        }
#pragma unroll
        for (int i = 0; i < 4; ++i)
#pragma unroll
          for (int j = 0; j < 9; ++j) acc[i][j] += ar[i] * tr[j];
      }
    }
#pragma unroll
    for (int i = 0; i < 4; ++i) {
      const int a = 1 + tv + 16 * i;
      _Float16* Fb = Fh + (size_t)b * FPP + (size_t)a * APLANE;   // v = 0
#pragma unroll
      for (int j = 0; j < 9; ++j) {
        const int w = tw + 16 * j;
        if (w < TE) {
          const float m = acc[i][j];
          Fb[w] = (_Float16)m;
          ss += m * m;
        }
      }
    }
  } else {
    float (*sa)[64] = (float(*)[64])smem;
    float (*sv)[64] = (float(*)[64])(smem + 10240);
    float* swt = (float*)(smem + 10240 + 8192);
    float acc[4][4];
#pragma unroll
    for (int i = 0; i < 4; ++i)
#pragma unroll
      for (int j = 0; j < 4; ++j) acc[i][j] = 0.f;

    for (int c = 0; c < 4; ++c) {
      const int s0 = 32 * c;
      __syncthreads();
      const float* abase = &audio[((size_t)(b * SS + s0)) * 64];
      const float* vbase = &vision[((size_t)(b * SS + s0)) * 64];
#pragma unroll
      for (int r = 0; r < 8; ++r) {
        const int e = tid + 256 * r;
        sa[e >> 6][e & 63] = abase[e];
        sv[e >> 6][e & 63] = vbase[e];
      }
      if (tid < 32) swt[tid] = text[((size_t)(b * SS + s0 + tid)) * 128 + 127];
      __syncthreads();
      for (int s = 0; s < 32; ++s) {
        const float t = swt[s];
        float ar[4], vr[4];
#pragma unroll
        for (int i = 0; i < 4; ++i) ar[i] = sa[s][tv + 16 * i] * t;
#pragma unroll
        for (int j = 0; j < 4; ++j) vr[j] = sv[s][tw + 16 * j];
#pragma unroll
        for (int i = 0; i < 4; ++i)
#pragma unroll
          for (int j = 0; j < 4; ++j) acc[i][j] += ar[i] * vr[j];
      }
    }
#pragma unroll
    for (int i = 0; i < 4; ++i) {
      const int a = 1 + tv + 16 * i;
      _Float16* Fb = Fh + (size_t)b * FPP + (size_t)a * APLANE;
#pragma unroll
      for (int j = 0; j < 4; ++j) {
        const int v = 1 + tw + 16 * j;
        float m = acc[i][j];
        ss += m * m;
        if (a == 64 && v == 64) { Flast[b] = m; m = 0.f; }  // exact fp32 path
        Fb[(size_t)v * VSTRIDE + 128] = (_Float16)m;
      }
    }
  }

#pragma unroll
  for (int off = 32; off > 0; off >>= 1) ss += __shfl_down(ss, off);
  if ((tid & 63) == 0) atomicAdd(&normsq[b], ss);
}

// ---------------- deep-K MFMA GEMM v11: COALESCED A via per-wave LDS transpose ----
// grid 1123 (KSP=512 -> 8 steps of 64 k). 4 waves; wave wv owns p-rows [32wv,+32).
// A: instr n reads 4 rows x 256B fully-coalesced (16 lanes/row); cvt f16 in regs;
//    ds_write_b64 to per-wave sA[32][64] (slot ^= row&7); fragments via ds_read_b128.
// B: sB[128][64k] f16 16KB double-buffer via gll16 (v10 pattern, unchanged).
__global__ __launch_bounds__(256) void k_gemm(
    const float* __restrict__ W1, const _Float16* __restrict__ Fh,
    float* __restrict__ parts)
{
  __shared__ _Float16 sB[2][8192];   // 2 x 16 KB
  __shared__ _Float16 sA[4][2048];   // per-wave 32 rows x 64 k f16 (4 KB each)

  const int tid = threadIdx.x;
  const int wv = tid >> 6, ln = tid & 63;
  const int lb = ln & 31, hb = ln >> 5;
  const int kp0 = blockIdx.x * KSP;

  // A-load geometry: instr n covers rows 32wv+4n+(ln>>4); lane k-offset (ln&15)*4
  const int loff = (ln & 15) << 2;          // float offset in 64-k window
  int wtr, kot;
  {
    const int kpl = kp0 + loff;
    const int a = kpl / APLANE;
    const int rem = kpl - a * APLANE;
    const int v = rem / VSTRIDE;
    wtr = rem - v * VSTRIDE;
    kot = a * 8385 + v * 129 + wtr;
  }
  const float* wbase = W1 + (size_t)((wv << 5) + (ln >> 4)) * FUSED;

  // B staging (v10): lane covers row brow, 16B slot sslot (pre-swizzled source)
  const int brow = (wv << 5) + (ln >> 3);
  const int sslot = (ln & 7) ^ ((ln >> 3) & 7);
  const _Float16* FhB = Fh + (size_t)brow * FPP + kp0 + (sslot << 3);

  f32x16 acc0 = {}, acc1 = {}, acc2 = {}, acc3 = {};
  float4 xa[8];

  // 4-float chunks never straddle VSTRIDE rows (136 % 4 == 0). Clamp ko<=545021
  // reads valid memory; clamped positions are pad holes/tail where Fh==0.
#define LOADA                                                              \
  {                                                                        \
    const int kc = (kot <= 545021) ? kot : 545021;                         \
    _Pragma("unroll")                                                      \
    for (int n = 0; n < 8; ++n)                                            \
      __builtin_memcpy(&xa[n], wbase + (size_t)(4 * n) * FUSED + kc, 16);  \
    wtr += 64;                                                             \
    if (wtr >= VSTRIDE) { wtr -= VSTRIDE; kot += 57; } else kot += 64;     \
  }

  // cvt + transpose into per-wave sA; slot = (loff/8) ^ (row&7), half = ln&1
#define WRITEA                                                             \
  {                                                                        \
    _Pragma("unroll")                                                      \
    for (int n = 0; n < 8; ++n) {                                          \
      const int Rl = 4 * n + (ln >> 4);                                    \
      const int sp = (((ln & 15) >> 1) ^ (Rl & 7));                        \
      half4 h;                                                             \
      h[0] = (_Float16)xa[n].x; h[1] = (_Float16)xa[n].y;                  \
      h[2] = (_Float16)xa[n].z; h[3] = (_Float16)xa[n].w;                  \
      *(half4*)((char*)&sA[wv][0] + (Rl << 7) + (sp << 4) + ((ln & 1) << 3)) = h; \
    }                                                                      \
  }

#define STAGEB(BUF, KOFF)                                                  \
  {                                                                        \
    _Pragma("unroll")                                                      \
    for (int n = 0; n < 4; ++n) {                                          \
      gll16(FhB + (size_t)(n << 3) * FPP + (KOFF),                         \
            (char*)&sB[BUF][0] + (((wv << 5) + (n << 3)) << 7));           \
    }                                                                      \
  }

  LOADA
  STAGEB(0, 0)
  __syncthreads();

  int buf = 0;
  for (int t = 0; t < NST; ++t) {
    WRITEA                              // xa(t) -> sA (per-wave, lgkm-ordered)
    if (t + 1 < NST) {
      LOADA                             // A(t+1) -> regs (drained by barrier)
      STAGEB(buf ^ 1, (t + 1) * 64)     // B(t+1) DMA
    }
    const _Float16* sBb = &sB[buf][0];
    const char* sAw = (const char*)&sA[wv][0] + (lb << 7);
#pragma unroll
    for (int j = 0; j < 4; ++j) {
      const half8 af = *(const half8*)(sAw + ((((j << 1) + hb) ^ (lb & 7)) << 4));
      const int slot = ((j << 1) + hb) ^ (lb & 7);
      const char* bbase = (const char*)sBb + (lb << 7) + (slot << 4);
      const half8 b0 = *(const half8*)(bbase);
      const half8 b1 = *(const half8*)(bbase + 4096);
      const half8 b2 = *(const half8*)(bbase + 8192);
      const half8 b3 = *(const half8*)(bbase + 12288);
      acc0 = __builtin_amdgcn_mfma_f32_32x32x16_f16(af, b0, acc0, 0, 0, 0);
      acc1 = __builtin_amdgcn_mfma_f32_32x32x16_f16(af, b1, acc1, 0, 0, 0);
      acc2 = __builtin_amdgcn_mfma_f32_32x32x16_f16(af, b2, acc2, 0, 0, 0);
      acc3 = __builtin_amdgcn_mfma_f32_32x32x16_f16(af, b3, acc3, 0, 0, 0);
    }
    __syncthreads();
    buf ^= 1;
  }
#undef LOADA
#undef WRITEA
#undef STAGEB

  // coalesced partial store: thread's 64 floats contiguous
  f32x16* o = (f32x16*)(parts + ((size_t)blockIdx.x * 256 + tid) * 64);
  o[0] = acc0; o[1] = acc1; o[2] = acc2; o[3] = acc3;
}

// ---------------- reduce partials -> y1pre[b][p] ----------------
__global__ __launch_bounds__(256) void k_red(const float* __restrict__ parts,
                                             float* __restrict__ y1pre)
{
  const int tid = threadIdx.x;
  const int T = blockIdx.x * 4 + (tid >> 6);
  const int R = tid & 63;
  float s = 0.f;
  for (int sl = blockIdx.y; sl < NBLK; sl += 16)
    s += parts[(size_t)sl * 16384 + T * 64 + R];
  const int wv2 = T >> 6, hb2 = (T >> 5) & 1, lb2 = T & 31;
  const int q = R >> 4, rg = R & 15;
  const int b = q * 32 + lb2;
  const int pp = wv2 * 32 + (rg & 3) + 8 * (rg >> 2) + 4 * hb2;
  atomicAdd(&y1pre[b * PFD + pp], s);
}

// ---------------- finalize: MLP per batch + (block 0) reg_loss ----------------
__global__ __launch_bounds__(128) void k_final(
    const float* __restrict__ y1pre, const float* __restrict__ b1,
    const float* __restrict__ W2, const float* __restrict__ b2,
    const float* __restrict__ W3, const float* __restrict__ b3,
    const float* __restrict__ W1, const float* __restrict__ Flast,
    const float* __restrict__ normsq, float* __restrict__ out)
{
  const int b = blockIdx.x, p = threadIdx.x;
  __shared__ float y1[PFD];
  __shared__ float red[PFD];
  const float extra = W1[(size_t)p * FUSED + (FUSED - 1)] * Flast[b];
  y1[p] = fmaxf(y1pre[(size_t)b * PFD + p] + extra + b1[p], 0.f);
  __syncthreads();
  float s = b2[p];
  for (int k = 0; k < PFD; ++k) s += y1[k] * W2[p * PFD + k];
  const float y2 = fmaxf(s, 0.f);
  red[p] = y2 * W3[p];
  __syncthreads();
  for (int off = 64; off > 0; off >>= 1) {
    if (p < off) red[p] += red[p + off];
    __syncthreads();
  }
  if (p == 0) {
    const float x = red[0] + b3[0];
    out[b] = 6.f / (1.f + expf(-x)) - 3.f;
  }
  if (b == 0) {   // fused k_reg: tmp = sqrt(64*64*128/128) = 64 exactly
    __syncthreads();
    red[p] = sqrtf(normsq[p]);
    __syncthreads();
    for (int off = 64; off > 0; off >>= 1) {
      if (p < off) red[p] += red[p + off];
      __syncthreads();
    }
    if (p == 0) out[BB] = 64.f * red[0] / (float)BB;
  }
}

extern "C" void kernel_launch(void* const* d_in, const int* in_sizes, int n_in,
                              void* d_out, int out_size, void* d_ws, size_t ws_size,
                              hipStream_t stream) {
  const float* audio  = (const float*)d_in[0];
  const float* vision = (const float*)d_in[1];
  const float* text   = (const float*)d_in[2];
  const float* W1     = (const float*)d_in[3];
  const float* b1     = (const float*)d_in[4];
  const float* W2     = (const float*)d_in[5];
  const float* b2     = (const float*)d_in[6];
  const float* W3     = (const float*)d_in[7];
  const float* b3     = (const float*)d_in[8];
  float* out = (float*)d_out;

  // ws layout (proven bound ws >= 279,183,872 B):
  // [y1pre 64KB][normsq][Flast] | Fh @131072 (147,193,856 B) |
  // parts @147,324,928 (1123*64KB = 73,596,928 B) -> total 220,921,856 B
  float* y1pre  = (float*)d_ws;
  float* normsq = y1pre + BB * PFD;
  float* Flast  = normsq + BB;
  _Float16* Fh  = (_Float16*)((char*)d_ws + 131072);
  float* parts  = (float*)((char*)d_ws + 147324928);

  k_initf<<<BB, 256, 0, stream>>>(Fh, y1pre, normsq, Flast);

  k_core<<<dim3(BB, 8, 2), 256, 0, stream>>>(audio, vision, text, Fh, normsq);
  k_planes<<<dim3(BB, 3), 256, 0, stream>>>(audio, vision, text, Fh, Flast, normsq);

  k_gemm<<<NBLK, 256, 0, stream>>>(W1, Fh, parts);
  k_red<<<dim3(64, 16), 256, 0, stream>>>(parts, y1pre);

  k_final<<<BB, PFD, 0, stream>>>(y1pre, b1, W2, b2, W3, b3, W1, Flast, normsq, out);
}